// Round 20
// baseline (412.241 us; speedup 1.0000x reference)
//
#include <hip/hip_runtime.h>

#define DEVI __device__ __forceinline__

typedef __attribute__((ext_vector_type(8))) short s8v;   // 8 x bf16 bits = 4 VGPRs
typedef __attribute__((ext_vector_type(4))) float f4v;   // MFMA accumulator

DEVI unsigned short f2bf(float f) {
  unsigned int u = __float_as_uint(f);
  return (unsigned short)((u + 0x7FFFu + ((u >> 16) & 1u)) >> 16);  // RNE
}
DEVI float bf2f(unsigned short h) { return __uint_as_float(((unsigned int)h) << 16); }

DEVI f4v mfma16(s8v a, s8v b, f4v c) {
  asm("v_mfma_f32_16x16x32_bf16 %0, %1, %2, %0" : "+v"(c) : "v"(a), "v"(b));
  return c;
}

DEVI float fexp2(float x) {  // 2^x via v_exp_f32
  float r;
  asm("v_exp_f32 %0, %1" : "=v"(r) : "v"(x));
  return r;
}

DEVI unsigned int cvtpk_bf16(float lo, float hi) {  // word0=bf16(lo), word1=bf16(hi)
  unsigned int r;
  asm("v_cvt_pk_bf16_f32 %0, %1, %2" : "=v"(r) : "v"(lo), "v"(hi));
  return r;
}

// tanh-form gelu: gelu(x) = x * sigmoid(2.302258*x + 0.102956*x^3); max |err| ~5e-4
DEVI float gelu_t(float x) {
  const float t = x * x;
  const float a = __builtin_fmaf(t, -0.10295555f, -2.30225854f);
  return x / (1.0f + fexp2(x * a));
}

DEVI void gload_lds16(const void* g, void* l) {
  __builtin_amdgcn_global_load_lds(
      (__attribute__((address_space(1))) void*)g,
      (__attribute__((address_space(3))) void*)l, 16, 0, 0);
}

DEVI void barrier_raw() {  // s_barrier with compiler fences, no vmcnt drain
  asm volatile("" ::: "memory");
  __builtin_amdgcn_s_barrier();
  asm volatile("" ::: "memory");
}

// Supertile map: per XCD, 8 consecutive by share each bx step (8 blocks
// share one B panel; A panels 8x256KB stay L2-resident). Requires
// nblocks == 64 * nbx (rows-per-XCD == 8).
DEVI void map_block(int bid, int nbx, int gw, int& by, int& bx) {
  const int xcd = bid & 7;
  const int local = bid >> 3;
  const int grp = gw * 8;
  const int q = local / grp;
  const int rem = local - q * grp;
  by = xcd * 8 + (rem & 7);
  bx = q * gw + (rem >> 3);
}

// ---------------------------------------------------------------------------
// Merged preprocessing: one launch.
//   blocks [0, 16384): weight convert (Wqkv/Wout/W2 straight, W1/W3 interleave)
//   blocks [16384, 24576): rmsnorm(src, g1) -> xn (bf16)
//   blocks [24576, 24832): RoPE cos/sin table
__global__ __launch_bounds__(256)
void prep_k(const float* __restrict__ Wqkv, const float* __restrict__ Wout,
            const float* __restrict__ W2, const float* __restrict__ W1,
            const float* __restrict__ W3,
            unsigned short* __restrict__ wQKV, unsigned short* __restrict__ wOut,
            unsigned short* __restrict__ wW2, unsigned short* __restrict__ wI,
            const float* __restrict__ src, const float* __restrict__ g1,
            unsigned short* __restrict__ xn,
            float* __restrict__ cosT, float* __restrict__ sinT) {
  const int bid = blockIdx.x;
  const int tid = threadIdx.x;
  if (bid < 16384) {
    const int i = bid * 256 + tid;          // 0 .. 4194303
    const float4* s;
    ushort4* d;
    if (i < 786432) {                       // Wqkv: 3072x1024
      s = (const float4*)Wqkv + i;
      d = (ushort4*)wQKV + i;
    } else if (i < 1048576) {               // Wout: 1024x1024
      const int j = i - 786432;
      s = (const float4*)Wout + j;
      d = (ushort4*)wOut + j;
    } else if (i < 2097152) {               // W2: 1024x4096
      const int j = i - 1048576;
      s = (const float4*)W2 + j;
      d = (ushort4*)wW2 + j;
    } else {                                // W1/W3 interleave -> wI [8192,1024]
      const int j = i - 2097152;
      const int g = j >> 8;
      const int c4 = j & 255;
      const int srow = ((g >> 7) << 6) + (g & 63);
      const float* sp = ((g >> 6) & 1) ? W3 : W1;
      s = (const float4*)(sp + (size_t)srow * 1024) + c4;
      d = (ushort4*)(wI + (size_t)g * 1024) + c4;
    }
    const float4 v = *s;
    ushort4 ov;
    ov.x = f2bf(v.x); ov.y = f2bf(v.y); ov.z = f2bf(v.z); ov.w = f2bf(v.w);
    *d = ov;
  } else if (bid < 24576) {
    const int row = bid - 16384;
    const float4 v = ((const float4*)(src + (size_t)row * 1024))[tid];
    float ss = v.x * v.x + v.y * v.y + v.z * v.z + v.w * v.w;
#pragma unroll
    for (int off = 32; off > 0; off >>= 1) ss += __shfl_down(ss, off);
    __shared__ float wsum[4];
    if ((tid & 63) == 0) wsum[tid >> 6] = ss;
    __syncthreads();
    const float tot = wsum[0] + wsum[1] + wsum[2] + wsum[3];
    const float sc = rsqrtf(tot * (1.0f / 1024.0f) + 1e-5f);
    const float4 gv = ((const float4*)g1)[tid];
    ushort4 ov;
    ov.x = f2bf(v.x * sc * gv.x);
    ov.y = f2bf(v.y * sc * gv.y);
    ov.z = f2bf(v.z * sc * gv.z);
    ov.w = f2bf(v.w * sc * gv.w);
    ((ushort4*)(xn + (size_t)row * 1024))[tid] = ov;
  } else {
    const int idx = (bid - 24576) * 256 + tid;   // 65536
    const int s = idx >> 5, p = idx & 31;
    const float inv = powf(10000.0f, -(float)(2 * p) * (1.0f / 64.0f));
    const float a = (float)s * inv;
    cosT[idx] = cosf(a);
    sinT[idx] = sinf(a);
  }
}

// ---------------------------------------------------------------------------
// RMSNorm (bf16 in): [8192,1024] * g -> bf16
__global__ __launch_bounds__(256)
void rmsnorm_b(const unsigned short* __restrict__ x, const float* __restrict__ g,
               unsigned short* __restrict__ o) {
  const int row = blockIdx.x;
  const int tid = threadIdx.x;
  const ushort4 hv = ((const ushort4*)(x + (size_t)row * 1024))[tid];
  float v0 = bf2f(hv.x), v1 = bf2f(hv.y), v2 = bf2f(hv.z), v3 = bf2f(hv.w);
  float ss = v0 * v0 + v1 * v1 + v2 * v2 + v3 * v3;
#pragma unroll
  for (int off = 32; off > 0; off >>= 1) ss += __shfl_down(ss, off);
  __shared__ float wsum[4];
  if ((tid & 63) == 0) wsum[tid >> 6] = ss;
  __syncthreads();
  const float tot = wsum[0] + wsum[1] + wsum[2] + wsum[3];
  const float sc = rsqrtf(tot * (1.0f / 1024.0f) + 1e-5f);
  const float4 gv = ((const float4*)g)[tid];
  ushort4 ov;
  ov.x = f2bf(v0 * sc * gv.x);
  ov.y = f2bf(v1 * sc * gv.y);
  ov.z = f2bf(v2 * sc * gv.z);
  ov.w = f2bf(v3 * sc * gv.w);
  ((ushort4*)(o + (size_t)row * 1024))[tid] = ov;
}

// ---------------------------------------------------------------------------
// GEMM C[M,N] = A[M,K] * Bt[N,K]^T, 128x128 tile + supertile map, PIPELINED
// K-loop (attn-style): one barrier/tile; tile t+1's loads are issued AFTER
// the barrier and stay in flight across compute(t); the vmcnt(0) at the top
// of iter t+1 waits loads that had a full compute phase to land (~free).
// Double-buffered LDS (64 KB). WAR on buf^1 closed by the collective barrier;
// RAW on buf closed by vmcnt(0)+barrier.
// EPI: 1 = QKV: Q/K blocks (bx<16) scatter with FUSED RoPE; V blocks (bx>=16)
//          write DIRECTLY TRANSPOSED to vT via the lower-32KB LDS scratch.
//      4 = fused W1W3 gelu-gate (interleaved weights), split across wave pair
//      5 = Cb = bf16(Xadd_f32 + acc)        (residual x, bf16 out)
//      6 = Cf = bf2f(Xb_bf16) + acc         (final out, f32; Xb passed via Qp)
template <int EPI>
__global__ __launch_bounds__(256)
void gemm_bt(const unsigned short* __restrict__ A,
             const unsigned short* __restrict__ Bt,
             const int K, const int N, const int nbx, const int gw,
             unsigned short* Cb, float* Cf, const float* Xadd,
             unsigned short* __restrict__ Qp, unsigned short* __restrict__ Kp,
             unsigned short* __restrict__ Vp,
             const float* __restrict__ cosT, const float* __restrict__ sinT) {
  __shared__ __align__(16) unsigned char smem[65536];
  const int tid = threadIdx.x;
  const int lane = tid & 63;
  const int wave = tid >> 6;
  const int wr = (wave >> 1) * 64, wc = (wave & 1) * 64;
  int by, bx;
  map_block(blockIdx.x, nbx, gw, by, bx);
  const int row0 = by * 128;
  const int col0 = bx * 128;

  int ldsOff[4], gOffA[4], gOffB[4];
#pragma unroll
  for (int it = 0; it < 4; ++it) {
    const int p = it * 4096 + tid * 16;
    const int row = p >> 7;
    const int inner = (p & 127) ^ ((row & 7) << 4);   // pre-swizzled global source
    ldsOff[it] = p;
    gOffA[it] = (row0 + row) * K + (inner >> 1);
    gOffB[it] = (col0 + row) * K + (inner >> 1);
  }

  f4v acc[4][4];
  const f4v fzero = {0.f, 0.f, 0.f, 0.f};
#pragma unroll
  for (int i = 0; i < 4; ++i)
#pragma unroll
    for (int j = 0; j < 4; ++j) acc[i][j] = fzero;

  const int cbase = (lane >> 4) * 16;
  const int rlane = lane & 15;

  // prologue: stage K-tile 0 into buffer 0
#pragma unroll
  for (int it = 0; it < 4; ++it) {
    gload_lds16(A + gOffA[it], smem + ldsOff[it]);
    gload_lds16(Bt + gOffB[it], smem + 16384 + ldsOff[it]);
  }

  for (int kt = 0, t = 0; kt < K; kt += 64, ++t) {
    const int buf = t & 1;
    const unsigned char* cA = smem + buf * 32768;
    const unsigned char* cB = cA + 16384;
    asm volatile("s_waitcnt vmcnt(0)" ::: "memory");   // tile t's 8 loads (issued
    barrier_raw();                                     // a full iter ago) landed
    if (kt + 64 < K) {   // stage t+1 AFTER barrier (WAR-safe), in flight below
      unsigned char* nA = smem + (buf ^ 1) * 32768;
      unsigned char* nB = nA + 16384;
#pragma unroll
      for (int it = 0; it < 4; ++it) {
        gload_lds16(A + gOffA[it] + kt + 64, nA + ldsOff[it]);
        gload_lds16(Bt + gOffB[it] + kt + 64, nB + ldsOff[it]);
      }
    }

#pragma unroll
    for (int ks = 0; ks < 2; ++ks) {
      const int cb = ks * 64 + cbase;
      s8v af[4], bfv[4];
#pragma unroll
      for (int i = 0; i < 4; ++i) {
        const int r = wr + i * 16 + rlane;
        af[i] = *(const s8v*)(cA + r * 128 + (cb ^ ((r & 7) << 4)));
      }
#pragma unroll
      for (int j = 0; j < 4; ++j) {
        const int r = wc + j * 16 + rlane;
        bfv[j] = *(const s8v*)(cB + r * 128 + (cb ^ ((r & 7) << 4)));
      }
      __builtin_amdgcn_s_setprio(1);
#pragma unroll
      for (int i = 0; i < 4; ++i)
#pragma unroll
        for (int j = 0; j < 4; ++j) acc[i][j] = mfma16(af[i], bfv[j], acc[i][j]);
      __builtin_amdgcn_s_setprio(0);
    }
  }

  const int rquad = (lane >> 4) * 4;

  if constexpr (EPI == 4) {
    // pair (even=h1, odd=h3) shares rows [wr, wr+64); split rows across pair.
    // Column XOR'd by (t>>2)&1 -> 2-way banks (free).
    __syncthreads();
    float* xbuf = (wave & 2) ? (float*)(smem + 16384) : (float*)smem;  // 16 KB/pair
    if (wave & 1) {
#pragma unroll
      for (int i = 0; i < 2; ++i)
#pragma unroll
        for (int j = 0; j < 4; ++j)
#pragma unroll
          for (int r = 0; r < 4; ++r) {
            const int t = i * 16 + rquad + r;
            const int cs = (j * 16 + rlane) ^ (((t >> 2) & 1) << 4);
            xbuf[(t << 6) + cs] = acc[i][j][r];
          }
    } else {
#pragma unroll
      for (int i = 0; i < 2; ++i)
#pragma unroll
        for (int j = 0; j < 4; ++j)
#pragma unroll
          for (int r = 0; r < 4; ++r) {
            const int t = i * 16 + rquad + r;
            const int cs = (j * 16 + rlane) ^ (((t >> 2) & 1) << 4);
            xbuf[2048 + (t << 6) + cs] = acc[2 + i][j][r];
          }
    }
    __syncthreads();
    if (!(wave & 1)) {
#pragma unroll
      for (int i = 0; i < 2; ++i)
#pragma unroll
        for (int j = 0; j < 4; ++j)
#pragma unroll
          for (int r = 0; r < 4; ++r) {
            const int t = i * 16 + rquad + r;
            const int cs = (j * 16 + rlane) ^ (((t >> 2) & 1) << 4);
            const float h1v = acc[i][j][r];
            const float h3v = xbuf[(t << 6) + cs];
            Cb[(size_t)(row0 + wr + t) * N + (size_t)bx * 64 + j * 16 + rlane] =
                f2bf(gelu_t(h1v) * h3v);
          }
    } else {
#pragma unroll
      for (int i = 0; i < 2; ++i)
#pragma unroll
        for (int j = 0; j < 4; ++j)
#pragma unroll
          for (int r = 0; r < 4; ++r) {
            const int t = i * 16 + rquad + r;
            const int cs = (j * 16 + rlane) ^ (((t >> 2) & 1) << 4);
            const float h1v = xbuf[2048 + (t << 6) + cs];
            const float h3v = acc[2 + i][j][r];
            Cb[(size_t)(row0 + wr + 32 + t) * N + (size_t)bx * 64 + j * 16 + rlane] =
                f2bf(gelu_t(h1v) * h3v);
          }
    }
    return;
  }

  if constexpr (EPI == 1) {
    if (bx >= 16) {
      // V block: transpose 128s x 128c through lower-32KB LDS, write vT coalesced.
      __syncthreads();   // all waves done with the K-loop buffers
#pragma unroll
      for (int i = 0; i < 4; ++i) {
#pragma unroll
        for (int j = 0; j < 4; ++j) {
#pragma unroll
          for (int rp = 0; rp < 4; rp += 2) {
            const int c = wc + j * 16 + rlane;
            const int s = wr + i * 16 + rquad + rp;
            const unsigned int u = cvtpk_bf16(acc[i][j][rp], acc[i][j][rp + 1]);
            *(unsigned int*)(smem + c * 256 + ((2 * s) ^ ((c & 7) << 4))) = u;
          }
        }
      }
      __syncthreads();
      const int b = row0 >> 11, s0 = row0 & 2047;
      const int hbase = (bx - 16) * 2;
#pragma unroll
      for (int t8 = 0; t8 < 8; ++t8) {
        const int gidx = t8 * 256 + tid;       // 0..2047
        const int c = gidx >> 4, ch = gidx & 15;
        s8v val = *(const s8v*)(smem + c * 256 + ((ch * 16) ^ ((c & 7) << 4)));
        const int bh = b * 16 + hbase + (c >> 6);
        const int d = c & 63;
        *(s8v*)(Vp + ((size_t)bh * 64 + d) * 2048 + s0 + ch * 8) = val;
      }
      return;
    }
    // Q/K block: fused RoPE scatter (bx<16 -> which in {0,1})
#pragma unroll
    for (int i = 0; i < 4; ++i) {
#pragma unroll
      for (int j = 0; j < 4; ++j) {
#pragma unroll
        for (int r = 0; r < 4; ++r) {
          const int row = row0 + wr + i * 16 + rquad + r;
          const int col = col0 + wc + j * 16 + rlane;
          const float v = acc[i][j][r];
          const float partner = __shfl_xor(v, 1);
          const int which = col >> 10;
          const int rem = col & 1023;
          const int s = row & 2047;
          const int p = (rem & 63) >> 1;
          const float c = cosT[(s << 5) + p];
          const float sn = sinT[(s << 5) + p];
          const float sg = (rem & 1) ? sn : -sn;
          const float roped = __builtin_fmaf(partner, sg, v * c);
          const size_t idx =
              (((size_t)(row >> 11) * 16 + (rem >> 6)) * 2048 + (row & 2047)) * 64 + (rem & 63);
          if (which == 0) Qp[idx] = f2bf(roped * (0.125f * 1.44269504089f));
          else Kp[idx] = f2bf(roped);
        }
      }
    }
    return;
  }

#pragma unroll
  for (int i = 0; i < 4; ++i) {
#pragma unroll
    for (int j = 0; j < 4; ++j) {
#pragma unroll
      for (int r = 0; r < 4; ++r) {
        const int row = row0 + wr + i * 16 + rquad + r;
        const int col = col0 + wc + j * 16 + rlane;
        const float v = acc[i][j][r];
        if constexpr (EPI == 5) {
          const size_t idx = (size_t)row * N + col;
          Cb[idx] = f2bf(Xadd[idx] + v);
        } else if constexpr (EPI == 6) {
          const size_t idx = (size_t)row * N + col;
          Cf[idx] = bf2f(Qp[idx]) + v;
        }
      }
    }
  }
}

// ---------------------------------------------------------------------------
// Flash attention fwd, QBLK=128, 4 waves x 32 q-rows, static-max softmax,
// single barrier/iter, KEY-PERMUTED K staging (P stays in registers).
// __launch_bounds__(256,4): cap VGPR at 128 -> 4 blocks/CU (latency hiding).
__global__ __launch_bounds__(256, 4)
void attn_k(const unsigned short* __restrict__ Qg,
            const unsigned short* __restrict__ Kg,
            const unsigned short* __restrict__ VTg,
            unsigned short* __restrict__ Og) {
  __shared__ __align__(16) unsigned char sK[2][8192];
  __shared__ __align__(16) unsigned char sV[2][8192];

  const int tid = threadIdx.x, lane = tid & 63, wave = tid >> 6;  // wave 0..3
  int id = blockIdx.x;
  id = (id & 7) * 128 + (id >> 3);               // XCD swizzle, 1024 blocks
  const int qt = id & 15, h = (id >> 4) & 15, b = id >> 8;
  const size_t bh = (size_t)b * 16 + h;
  const unsigned short* qb = Qg + (bh * 2048 + (size_t)qt * 128 + wave * 32) * 64;
  const unsigned short* kbp = Kg + bh * 2048 * 64;
  const unsigned short* vb = VTg + bh * 64 * 2048;

  const int g = lane >> 4;
  const int rl = lane & 15;
  const int cbase = g * 16;

  s8v qf[2][2];
#pragma unroll
  for (int qs = 0; qs < 2; ++qs) {
    const unsigned short* qrow = qb + (size_t)(qs * 16 + rl) * 64 + g * 8;
    qf[qs][0] = *(const s8v*)(qrow);
    qf[qs][1] = *(const s8v*)(qrow + 32);
  }

  const f4v fzero = {0.f, 0.f, 0.f, 0.f};
  f4v of[2][4];
#pragma unroll
  for (int qs = 0; qs < 2; ++qs)
#pragma unroll
    for (int jd = 0; jd < 4; ++jd) of[qs][jd] = fzero;
  float l[2] = {0.f, 0.f};   // per-lane partials; reduced at end

  // staging: 256 threads x 2 x 16B per 8KB tile; K source row = kappa(row)
  int ldsOff[2], koff[2], voff[2];
#pragma unroll
  for (int it = 0; it < 2; ++it) {
    const int p = it * 4096 + tid * 16;
    const int row = p >> 7;
    const int krow = (row & 32) | ((row & 12) << 1) | ((row & 16) >> 2) | (row & 3);
    const int inner = (p & 127) ^ ((row & 7) << 4);
    ldsOff[it] = p;
    koff[it] = krow * 64 + (inner >> 1);
    voff[it] = row * 2048 + (inner >> 1);
  }

  // prologue: stage tile 0 into buf 0
#pragma unroll
  for (int it = 0; it < 2; ++it) {
    gload_lds16(kbp + koff[it], sK[0] + ldsOff[it]);
    gload_lds16(vb + voff[it], sV[0] + ldsOff[it]);
  }

  for (int t = 0; t < 32; ++t) {
    const int buf = t & 1;
    asm volatile("s_waitcnt vmcnt(0)" ::: "memory");   // only tile t outstanding
    barrier_raw();
    if (t < 31) {   // stage t+1 AFTER the barrier (WAR-safe), in flight below
      const size_t kt0 = (size_t)(t + 1) * 64;
#pragma unroll
      for (int it = 0; it < 2; ++it) {
        gload_lds16(kbp + kt0 * 64 + koff[it], sK[buf ^ 1] + ldsOff[it]);
        gload_lds16(vb + kt0 + voff[it], sV[buf ^ 1] + ldsOff[it]);
      }
    }

    // QK^T (swapped: A=K, B=Q); kf shared across both q-subtiles.
    f4v sc[2][4];
#pragma unroll
    for (int qs = 0; qs < 2; ++qs)
#pragma unroll
      for (int jk = 0; jk < 4; ++jk) sc[qs][jk] = fzero;
    __builtin_amdgcn_s_setprio(1);
#pragma unroll
    for (int ks = 0; ks < 2; ++ks) {
      const int cb = ks * 64 + cbase;
#pragma unroll
      for (int jk = 0; jk < 4; ++jk) {
        const int r = jk * 16 + rl;
        s8v kf = *(const s8v*)(sK[buf] + r * 128 + (cb ^ ((r & 7) << 4)));
        sc[0][jk] = mfma16(kf, qf[0][ks], sc[0][jk]);
        sc[1][jk] = mfma16(kf, qf[1][ks], sc[1][jk]);
      }
    }
    __builtin_amdgcn_s_setprio(0);

    // static-max softmax: P = exp2(sc) (bounded scores; m cancels in O/l)
#pragma unroll
    for (int qs = 0; qs < 2; ++qs) {
      float rs = 0.f;
#pragma unroll
      for (int jk = 0; jk < 4; ++jk)
#pragma unroll
        for (int mm = 0; mm < 4; ++mm) {
          const float p = fexp2(sc[qs][jk][mm]);
          sc[qs][jk][mm] = p;
          rs += p;
        }
      l[qs] += rs;
    }

    // pa fully in-register: fragment jk holds physical keys
    // {32*(jk>>1) + g*8 + 4*(jk&1) + mm}  ->  pa[ks] = sc[2ks] ++ sc[2ks+1].
    s8v pa[2][2];
#pragma unroll
    for (int qs = 0; qs < 2; ++qs) {
#pragma unroll
      for (int ks = 0; ks < 2; ++ks) {
        union { s8v v; unsigned int u[4]; } pk;
        pk.u[0] = cvtpk_bf16(sc[qs][2 * ks][0], sc[qs][2 * ks][1]);
        pk.u[1] = cvtpk_bf16(sc[qs][2 * ks][2], sc[qs][2 * ks][3]);
        pk.u[2] = cvtpk_bf16(sc[qs][2 * ks + 1][0], sc[qs][2 * ks + 1][1]);
        pk.u[3] = cvtpk_bf16(sc[qs][2 * ks + 1][2], sc[qs][2 * ks + 1][3]);
        pa[qs][ks] = pk.v;
      }
    }

    // O += P * V : one vf read feeds both q-subtiles.
    __builtin_amdgcn_s_setprio(1);
#pragma unroll
    for (int ks = 0; ks < 2; ++ks) {
      const int cb = ks * 64 + cbase;
#pragma unroll
      for (int jd = 0; jd < 4; ++jd) {
        const int r = jd * 16 + rl;
        s8v vf = *(const s8v*)(sV[buf] + r * 128 + (cb ^ ((r & 7) << 4)));
        of[0][jd] = mfma16(pa[0][ks], vf, of[0][jd]);
        of[1][jd] = mfma16(pa[1][ks], vf, of[1][jd]);
      }
    }
    __builtin_amdgcn_s_setprio(0);
  }

#pragma unroll
  for (int qs = 0; qs < 2; ++qs) {
    float lt = l[qs];
    lt += __shfl_xor(lt, 16);
    lt += __shfl_xor(lt, 32);
    const float inv = 1.0f / lt;
#pragma unroll
    for (int r = 0; r < 4; ++r) {
      const float ivr = __shfl(inv, g * 20 + r);
      const int qrow = qt * 128 + wave * 32 + qs * 16 + g * 4 + r;
      const size_t obase = ((size_t)b * 2048 + qrow) * 1024 + h * 64;
#pragma unroll
      for (int jd = 0; jd < 4; ++jd) Og[obase + jd * 16 + rl] = f2bf(of[qs][jd][r] * ivr);
    }
  }
}

// ---------------------------------------------------------------------------
extern "C" void kernel_launch(void* const* d_in, const int* in_sizes, int n_in,
                              void* d_out, int out_size, void* d_ws, size_t ws_size,
                              hipStream_t stream) {
  (void)in_sizes; (void)n_in; (void)out_size; (void)ws_size;
  const float* src  = (const float*)d_in[0];
  const float* Wqkv = (const float*)d_in[1];
  const float* Wout = (const float*)d_in[2];
  const float* g1   = (const float*)d_in[3];
  const float* g2   = (const float*)d_in[4];
  const float* W1   = (const float*)d_in[5];
  const float* W2   = (const float*)d_in[6];
  const float* W3   = (const float*)d_in[7];
  float* out = (float*)d_out;

  char* ws = (char*)d_ws;
  size_t off = 0;
  auto take = [&](size_t bytes) -> char* {
    char* p = ws + off;
    off += (bytes + 255) & ~(size_t)255;
    return p;
  };
  unsigned short* wQKV = (unsigned short*)take((size_t)3072 * 1024 * 2);
  unsigned short* wOut = (unsigned short*)take((size_t)1024 * 1024 * 2);
  unsigned short* wI   = (unsigned short*)take((size_t)8192 * 1024 * 2);  // W1/W3 interleaved
  unsigned short* wW2  = (unsigned short*)take((size_t)1024 * 4096 * 2);
  unsigned short* xn   = (unsigned short*)take((size_t)8192 * 1024 * 2);  // xn / attnO / xn2
  unsigned short* q    = (unsigned short*)take((size_t)64 * 2048 * 64 * 2);  // Q heads / xb
  unsigned short* kb   = (unsigned short*)take((size_t)64 * 2048 * 64 * 2);
  unsigned short* vT   = (unsigned short*)take((size_t)64 * 64 * 2048 * 2);
  float* cosT = (float*)take((size_t)2048 * 32 * 4);
  float* sinT = (float*)take((size_t)2048 * 32 * 4);
  unsigned short* h1   = (unsigned short*)take((size_t)8192 * 4096 * 2);  // gelu(h1)*h3

  // merged prep: weight converts + rmsnorm(src,g1) + rope table
  prep_k<<<dim3(24832), dim3(256), 0, stream>>>(Wqkv, Wout, W2, W1, W3,
                                                wQKV, wOut, wW2, wI,
                                                src, g1, xn, cosT, sinT);
  // qkv = xn @ Wqkv^T -> q/k (RoPE fused) + vT (transposed in-epilogue)
  gemm_bt<1><<<dim3(1536), dim3(256), 0, stream>>>(xn, wQKV, 1024, 3072, 24, 8,
                                                   nullptr, nullptr, nullptr, q, kb, vT, cosT, sinT);
  // attnO -> xn  [B,S,1024]  (4 waves, key-permuted K, P in registers)
  attn_k<<<dim3(1024), dim3(256), 0, stream>>>(q, kb, vT, xn);
  // xb = bf16(src + attnO @ Wout^T)   (reuse q buffer)
  gemm_bt<5><<<dim3(512), dim3(256), 0, stream>>>(xn, wOut, 1024, 1024, 8, 4,
                                                  q, nullptr, src, nullptr, nullptr, nullptr,
                                                  nullptr, nullptr);
  // xn2 = rmsnorm(xb, g2)
  rmsnorm_b<<<dim3(8192), dim3(256), 0, stream>>>(q, g2, xn);
  // h1 = gelu(xn2 @ W1^T) * (xn2 @ W3^T)   (fused, interleaved weights)
  gemm_bt<4><<<dim3(4096), dim3(256), 0, stream>>>(xn, wI, 1024, 4096, 64, 8,
                                                   h1, nullptr, nullptr, nullptr, nullptr, nullptr,
                                                   nullptr, nullptr);
  // out = xb + h1 @ W2^T   (f32 final)
  gemm_bt<6><<<dim3(512), dim3(256), 0, stream>>>(h1, wW2, 4096, 1024, 8, 2,
                                                  nullptr, out, nullptr, q, nullptr, nullptr,
                                                  nullptr, nullptr);
}

// Round 21
// 404.349 us; speedup vs baseline: 1.0195x; 1.0195x over previous
//
#include <hip/hip_runtime.h>

#define DEVI __device__ __forceinline__

typedef __attribute__((ext_vector_type(8))) short s8v;   // 8 x bf16 bits = 4 VGPRs
typedef __attribute__((ext_vector_type(4))) float f4v;   // MFMA accumulator

DEVI unsigned short f2bf(float f) {
  unsigned int u = __float_as_uint(f);
  return (unsigned short)((u + 0x7FFFu + ((u >> 16) & 1u)) >> 16);  // RNE
}
DEVI float bf2f(unsigned short h) { return __uint_as_float(((unsigned int)h) << 16); }

DEVI f4v mfma16(s8v a, s8v b, f4v c) {
  asm("v_mfma_f32_16x16x32_bf16 %0, %1, %2, %0" : "+v"(c) : "v"(a), "v"(b));
  return c;
}

DEVI float fexp2(float x) {  // 2^x via v_exp_f32
  float r;
  asm("v_exp_f32 %0, %1" : "=v"(r) : "v"(x));
  return r;
}

DEVI unsigned int cvtpk_bf16(float lo, float hi) {  // word0=bf16(lo), word1=bf16(hi)
  unsigned int r;
  asm("v_cvt_pk_bf16_f32 %0, %1, %2" : "=v"(r) : "v"(lo), "v"(hi));
  return r;
}

// tanh-form gelu: gelu(x) = x * sigmoid(2.302258*x + 0.102956*x^3); max |err| ~5e-4
DEVI float gelu_t(float x) {
  const float t = x * x;
  const float a = __builtin_fmaf(t, -0.10295555f, -2.30225854f);
  return x / (1.0f + fexp2(x * a));
}

DEVI void gload_lds16(const void* g, void* l) {
  __builtin_amdgcn_global_load_lds(
      (__attribute__((address_space(1))) void*)g,
      (__attribute__((address_space(3))) void*)l, 16, 0, 0);
}

DEVI void barrier_raw() {  // s_barrier with compiler fences, no vmcnt drain
  asm volatile("" ::: "memory");
  __builtin_amdgcn_s_barrier();
  asm volatile("" ::: "memory");
}

// Supertile map: per XCD, 8 consecutive by share each bx step (8 blocks
// share one B panel; A panels 8x256KB stay L2-resident). Requires
// nblocks == 64 * nbx (rows-per-XCD == 8).
DEVI void map_block(int bid, int nbx, int gw, int& by, int& bx) {
  const int xcd = bid & 7;
  const int local = bid >> 3;
  const int grp = gw * 8;
  const int q = local / grp;
  const int rem = local - q * grp;
  by = xcd * 8 + (rem & 7);
  bx = q * gw + (rem >> 3);
}

// ---------------------------------------------------------------------------
// Merged preprocessing: one launch.
//   blocks [0, 16384): weight convert (Wqkv/Wout/W2 straight, W1/W3 interleave)
//   blocks [16384, 24576): rmsnorm(src, g1) -> xn (bf16)
//   blocks [24576, 24832): RoPE cos/sin table
__global__ __launch_bounds__(256)
void prep_k(const float* __restrict__ Wqkv, const float* __restrict__ Wout,
            const float* __restrict__ W2, const float* __restrict__ W1,
            const float* __restrict__ W3,
            unsigned short* __restrict__ wQKV, unsigned short* __restrict__ wOut,
            unsigned short* __restrict__ wW2, unsigned short* __restrict__ wI,
            const float* __restrict__ src, const float* __restrict__ g1,
            unsigned short* __restrict__ xn,
            float* __restrict__ cosT, float* __restrict__ sinT) {
  const int bid = blockIdx.x;
  const int tid = threadIdx.x;
  if (bid < 16384) {
    const int i = bid * 256 + tid;          // 0 .. 4194303
    const float4* s;
    ushort4* d;
    if (i < 786432) {                       // Wqkv: 3072x1024
      s = (const float4*)Wqkv + i;
      d = (ushort4*)wQKV + i;
    } else if (i < 1048576) {               // Wout: 1024x1024
      const int j = i - 786432;
      s = (const float4*)Wout + j;
      d = (ushort4*)wOut + j;
    } else if (i < 2097152) {               // W2: 1024x4096
      const int j = i - 1048576;
      s = (const float4*)W2 + j;
      d = (ushort4*)wW2 + j;
    } else {                                // W1/W3 interleave -> wI [8192,1024]
      const int j = i - 2097152;
      const int g = j >> 8;
      const int c4 = j & 255;
      const int srow = ((g >> 7) << 6) + (g & 63);
      const float* sp = ((g >> 6) & 1) ? W3 : W1;
      s = (const float4*)(sp + (size_t)srow * 1024) + c4;
      d = (ushort4*)(wI + (size_t)g * 1024) + c4;
    }
    const float4 v = *s;
    ushort4 ov;
    ov.x = f2bf(v.x); ov.y = f2bf(v.y); ov.z = f2bf(v.z); ov.w = f2bf(v.w);
    *d = ov;
  } else if (bid < 24576) {
    const int row = bid - 16384;
    const float4 v = ((const float4*)(src + (size_t)row * 1024))[tid];
    float ss = v.x * v.x + v.y * v.y + v.z * v.z + v.w * v.w;
#pragma unroll
    for (int off = 32; off > 0; off >>= 1) ss += __shfl_down(ss, off);
    __shared__ float wsum[4];
    if ((tid & 63) == 0) wsum[tid >> 6] = ss;
    __syncthreads();
    const float tot = wsum[0] + wsum[1] + wsum[2] + wsum[3];
    const float sc = rsqrtf(tot * (1.0f / 1024.0f) + 1e-5f);
    const float4 gv = ((const float4*)g1)[tid];
    ushort4 ov;
    ov.x = f2bf(v.x * sc * gv.x);
    ov.y = f2bf(v.y * sc * gv.y);
    ov.z = f2bf(v.z * sc * gv.z);
    ov.w = f2bf(v.w * sc * gv.w);
    ((ushort4*)(xn + (size_t)row * 1024))[tid] = ov;
  } else {
    const int idx = (bid - 24576) * 256 + tid;   // 65536
    const int s = idx >> 5, p = idx & 31;
    const float inv = powf(10000.0f, -(float)(2 * p) * (1.0f / 64.0f));
    const float a = (float)s * inv;
    cosT[idx] = cosf(a);
    sinT[idx] = sinf(a);
  }
}

// ---------------------------------------------------------------------------
// RMSNorm (bf16 in): [8192,1024] * g -> bf16
__global__ __launch_bounds__(256)
void rmsnorm_b(const unsigned short* __restrict__ x, const float* __restrict__ g,
               unsigned short* __restrict__ o) {
  const int row = blockIdx.x;
  const int tid = threadIdx.x;
  const ushort4 hv = ((const ushort4*)(x + (size_t)row * 1024))[tid];
  float v0 = bf2f(hv.x), v1 = bf2f(hv.y), v2 = bf2f(hv.z), v3 = bf2f(hv.w);
  float ss = v0 * v0 + v1 * v1 + v2 * v2 + v3 * v3;
#pragma unroll
  for (int off = 32; off > 0; off >>= 1) ss += __shfl_down(ss, off);
  __shared__ float wsum[4];
  if ((tid & 63) == 0) wsum[tid >> 6] = ss;
  __syncthreads();
  const float tot = wsum[0] + wsum[1] + wsum[2] + wsum[3];
  const float sc = rsqrtf(tot * (1.0f / 1024.0f) + 1e-5f);
  const float4 gv = ((const float4*)g)[tid];
  ushort4 ov;
  ov.x = f2bf(v0 * sc * gv.x);
  ov.y = f2bf(v1 * sc * gv.y);
  ov.z = f2bf(v2 * sc * gv.z);
  ov.w = f2bf(v3 * sc * gv.w);
  ((ushort4*)(o + (size_t)row * 1024))[tid] = ov;
}

// ---------------------------------------------------------------------------
// GEMM C[M,N] = A[M,K] * Bt[N,K]^T (m97 structure) + supertile block map.
// EPI: 1 = QKV: Q/K blocks (bx<16) scatter with FUSED RoPE; V blocks (bx>=16)
//          write DIRECTLY TRANSPOSED to vT via the (free) 32KB LDS.
//      4 = fused W1W3 gelu-gate (interleaved weights), split across wave pair
//      5 = Cb = bf16(Xadd_f32 + acc)        (residual x, bf16 out)
//      6 = Cf = bf2f(Xb_bf16) + acc         (final out, f32; Xb passed via Qp)
template <int EPI>
__global__ __launch_bounds__(256)
void gemm_bt(const unsigned short* __restrict__ A,
             const unsigned short* __restrict__ Bt,
             const int K, const int N, const int nbx, const int gw,
             unsigned short* Cb, float* Cf, const float* Xadd,
             unsigned short* __restrict__ Qp, unsigned short* __restrict__ Kp,
             unsigned short* __restrict__ Vp,
             const float* __restrict__ cosT, const float* __restrict__ sinT) {
  __shared__ __align__(16) unsigned char smem[32768];
  unsigned char* sA = smem;
  unsigned char* sB = smem + 16384;
  const int tid = threadIdx.x;
  const int lane = tid & 63;
  const int wave = tid >> 6;
  const int wr = (wave >> 1) * 64, wc = (wave & 1) * 64;
  int by, bx;
  map_block(blockIdx.x, nbx, gw, by, bx);
  const int row0 = by * 128;
  const int col0 = bx * 128;

  int ldsOff[4], gOffA[4], gOffB[4];
#pragma unroll
  for (int it = 0; it < 4; ++it) {
    const int p = it * 4096 + tid * 16;
    const int row = p >> 7;
    const int inner = (p & 127) ^ ((row & 7) << 4);   // pre-swizzled global source
    ldsOff[it] = p;
    gOffA[it] = (row0 + row) * K + (inner >> 1);
    gOffB[it] = (col0 + row) * K + (inner >> 1);
  }

  f4v acc[4][4];
  const f4v fzero = {0.f, 0.f, 0.f, 0.f};
#pragma unroll
  for (int i = 0; i < 4; ++i)
#pragma unroll
    for (int j = 0; j < 4; ++j) acc[i][j] = fzero;

  const int cbase = (lane >> 4) * 16;
  const int rlane = lane & 15;

  for (int kt = 0; kt < K; kt += 64) {
    __syncthreads();
#pragma unroll
    for (int it = 0; it < 4; ++it) {
      gload_lds16(A + gOffA[it] + kt, sA + ldsOff[it]);
      gload_lds16(Bt + gOffB[it] + kt, sB + ldsOff[it]);
    }
    asm volatile("s_waitcnt vmcnt(0)" ::: "memory");
    __syncthreads();

#pragma unroll
    for (int ks = 0; ks < 2; ++ks) {
      const int cb = ks * 64 + cbase;
      s8v af[4], bfv[4];
#pragma unroll
      for (int i = 0; i < 4; ++i) {
        const int r = wr + i * 16 + rlane;
        af[i] = *(const s8v*)(sA + r * 128 + (cb ^ ((r & 7) << 4)));
      }
#pragma unroll
      for (int j = 0; j < 4; ++j) {
        const int r = wc + j * 16 + rlane;
        bfv[j] = *(const s8v*)(sB + r * 128 + (cb ^ ((r & 7) << 4)));
      }
#pragma unroll
      for (int i = 0; i < 4; ++i)
#pragma unroll
        for (int j = 0; j < 4; ++j) acc[i][j] = mfma16(af[i], bfv[j], acc[i][j]);
    }
  }

  const int rquad = (lane >> 4) * 4;

  if constexpr (EPI == 4) {
    // pair (even=h1, odd=h3) shares rows [wr, wr+64); split rows across pair.
    // Column XOR'd by (t>>2)&1 (= g parity) -> 2-way banks (free) vs 4-way.
    __syncthreads();
    float* xbuf = (wave & 2) ? (float*)sB : (float*)sA;   // 16 KB per pair
    if (wave & 1) {
#pragma unroll
      for (int i = 0; i < 2; ++i)
#pragma unroll
        for (int j = 0; j < 4; ++j)
#pragma unroll
          for (int r = 0; r < 4; ++r) {
            const int t = i * 16 + rquad + r;
            const int cs = (j * 16 + rlane) ^ (((t >> 2) & 1) << 4);
            xbuf[(t << 6) + cs] = acc[i][j][r];
          }
    } else {
#pragma unroll
      for (int i = 0; i < 2; ++i)
#pragma unroll
        for (int j = 0; j < 4; ++j)
#pragma unroll
          for (int r = 0; r < 4; ++r) {
            const int t = i * 16 + rquad + r;
            const int cs = (j * 16 + rlane) ^ (((t >> 2) & 1) << 4);
            xbuf[2048 + (t << 6) + cs] = acc[2 + i][j][r];
          }
    }
    __syncthreads();
    if (!(wave & 1)) {
#pragma unroll
      for (int i = 0; i < 2; ++i)
#pragma unroll
        for (int j = 0; j < 4; ++j)
#pragma unroll
          for (int r = 0; r < 4; ++r) {
            const int t = i * 16 + rquad + r;
            const int cs = (j * 16 + rlane) ^ (((t >> 2) & 1) << 4);
            const float h1v = acc[i][j][r];
            const float h3v = xbuf[(t << 6) + cs];
            Cb[(size_t)(row0 + wr + t) * N + (size_t)bx * 64 + j * 16 + rlane] =
                f2bf(gelu_t(h1v) * h3v);
          }
    } else {
#pragma unroll
      for (int i = 0; i < 2; ++i)
#pragma unroll
        for (int j = 0; j < 4; ++j)
#pragma unroll
          for (int r = 0; r < 4; ++r) {
            const int t = i * 16 + rquad + r;
            const int cs = (j * 16 + rlane) ^ (((t >> 2) & 1) << 4);
            const float h1v = xbuf[2048 + (t << 6) + cs];
            const float h3v = acc[2 + i][j][r];
            Cb[(size_t)(row0 + wr + 32 + t) * N + (size_t)bx * 64 + j * 16 + rlane] =
                f2bf(gelu_t(h1v) * h3v);
          }
    }
    return;
  }

  if constexpr (EPI == 1) {
    if (bx >= 16) {
      // V block: transpose 128s x 128c through LDS, write vT[bh][d][s] coalesced.
      __syncthreads();   // all waves done reading sA/sB in the K-loop
#pragma unroll
      for (int i = 0; i < 4; ++i) {
#pragma unroll
        for (int j = 0; j < 4; ++j) {
#pragma unroll
          for (int rp = 0; rp < 4; rp += 2) {
            const int c = wc + j * 16 + rlane;
            const int s = wr + i * 16 + rquad + rp;
            const unsigned int u = cvtpk_bf16(acc[i][j][rp], acc[i][j][rp + 1]);
            *(unsigned int*)(smem + c * 256 + ((2 * s) ^ ((c & 7) << 4))) = u;
          }
        }
      }
      __syncthreads();
      const int b = row0 >> 11, s0 = row0 & 2047;
      const int hbase = (bx - 16) * 2;
#pragma unroll
      for (int t8 = 0; t8 < 8; ++t8) {
        const int gidx = t8 * 256 + tid;       // 0..2047
        const int c = gidx >> 4, ch = gidx & 15;
        s8v val = *(const s8v*)(smem + c * 256 + ((ch * 16) ^ ((c & 7) << 4)));
        const int bh = b * 16 + hbase + (c >> 6);
        const int d = c & 63;
        *(s8v*)(Vp + ((size_t)bh * 64 + d) * 2048 + s0 + ch * 8) = val;
      }
      return;
    }
    // Q/K block: fused RoPE scatter (bx<16 -> which in {0,1})
#pragma unroll
    for (int i = 0; i < 4; ++i) {
#pragma unroll
      for (int j = 0; j < 4; ++j) {
#pragma unroll
        for (int r = 0; r < 4; ++r) {
          const int row = row0 + wr + i * 16 + rquad + r;
          const int col = col0 + wc + j * 16 + rlane;
          const float v = acc[i][j][r];
          const float partner = __shfl_xor(v, 1);
          const int which = col >> 10;
          const int rem = col & 1023;
          const int s = row & 2047;
          const int p = (rem & 63) >> 1;
          const float c = cosT[(s << 5) + p];
          const float sn = sinT[(s << 5) + p];
          const float sg = (rem & 1) ? sn : -sn;
          const float roped = __builtin_fmaf(partner, sg, v * c);
          const size_t idx =
              (((size_t)(row >> 11) * 16 + (rem >> 6)) * 2048 + (row & 2047)) * 64 + (rem & 63);
          if (which == 0) Qp[idx] = f2bf(roped * (0.125f * 1.44269504089f));
          else Kp[idx] = f2bf(roped);
        }
      }
    }
    return;
  }

#pragma unroll
  for (int i = 0; i < 4; ++i) {
#pragma unroll
    for (int j = 0; j < 4; ++j) {
#pragma unroll
      for (int r = 0; r < 4; ++r) {
        const int row = row0 + wr + i * 16 + rquad + r;
        const int col = col0 + wc + j * 16 + rlane;
        const float v = acc[i][j][r];
        if constexpr (EPI == 5) {
          const size_t idx = (size_t)row * N + col;
          Cb[idx] = f2bf(Xadd[idx] + v);
        } else if constexpr (EPI == 6) {
          const size_t idx = (size_t)row * N + col;
          Cf[idx] = bf2f(Qp[idx]) + v;
        }
      }
    }
  }
}

// ---------------------------------------------------------------------------
// Flash attention fwd, QBLK=128, 4 waves x 32 q-rows, static-max softmax,
// single barrier/iter, KEY-PERMUTED K staging (P stays in registers).
// __launch_bounds__(256,4): cap VGPR at 128 -> 4 blocks/CU (latency hiding).
__global__ __launch_bounds__(256, 4)
void attn_k(const unsigned short* __restrict__ Qg,
            const unsigned short* __restrict__ Kg,
            const unsigned short* __restrict__ VTg,
            unsigned short* __restrict__ Og) {
  __shared__ __align__(16) unsigned char sK[2][8192];
  __shared__ __align__(16) unsigned char sV[2][8192];

  const int tid = threadIdx.x, lane = tid & 63, wave = tid >> 6;  // wave 0..3
  int id = blockIdx.x;
  id = (id & 7) * 128 + (id >> 3);               // XCD swizzle, 1024 blocks
  const int qt = id & 15, h = (id >> 4) & 15, b = id >> 8;
  const size_t bh = (size_t)b * 16 + h;
  const unsigned short* qb = Qg + (bh * 2048 + (size_t)qt * 128 + wave * 32) * 64;
  const unsigned short* kbp = Kg + bh * 2048 * 64;
  const unsigned short* vb = VTg + bh * 64 * 2048;

  const int g = lane >> 4;
  const int rl = lane & 15;
  const int cbase = g * 16;

  s8v qf[2][2];
#pragma unroll
  for (int qs = 0; qs < 2; ++qs) {
    const unsigned short* qrow = qb + (size_t)(qs * 16 + rl) * 64 + g * 8;
    qf[qs][0] = *(const s8v*)(qrow);
    qf[qs][1] = *(const s8v*)(qrow + 32);
  }

  const f4v fzero = {0.f, 0.f, 0.f, 0.f};
  f4v of[2][4];
#pragma unroll
  for (int qs = 0; qs < 2; ++qs)
#pragma unroll
    for (int jd = 0; jd < 4; ++jd) of[qs][jd] = fzero;
  float l[2] = {0.f, 0.f};   // per-lane partials; reduced at end

  // staging: 256 threads x 2 x 16B per 8KB tile; K source row = kappa(row)
  int ldsOff[2], koff[2], voff[2];
#pragma unroll
  for (int it = 0; it < 2; ++it) {
    const int p = it * 4096 + tid * 16;
    const int row = p >> 7;
    const int krow = (row & 32) | ((row & 12) << 1) | ((row & 16) >> 2) | (row & 3);
    const int inner = (p & 127) ^ ((row & 7) << 4);
    ldsOff[it] = p;
    koff[it] = krow * 64 + (inner >> 1);
    voff[it] = row * 2048 + (inner >> 1);
  }

  // prologue: stage tile 0 into buf 0
#pragma unroll
  for (int it = 0; it < 2; ++it) {
    gload_lds16(kbp + koff[it], sK[0] + ldsOff[it]);
    gload_lds16(vb + voff[it], sV[0] + ldsOff[it]);
  }

  for (int t = 0; t < 32; ++t) {
    const int buf = t & 1;
    asm volatile("s_waitcnt vmcnt(0)" ::: "memory");   // only tile t outstanding
    barrier_raw();
    if (t < 31) {   // stage t+1 AFTER the barrier (WAR-safe), in flight below
      const size_t kt0 = (size_t)(t + 1) * 64;
#pragma unroll
      for (int it = 0; it < 2; ++it) {
        gload_lds16(kbp + kt0 * 64 + koff[it], sK[buf ^ 1] + ldsOff[it]);
        gload_lds16(vb + kt0 + voff[it], sV[buf ^ 1] + ldsOff[it]);
      }
    }

    // QK^T (swapped: A=K, B=Q); kf shared across both q-subtiles.
    f4v sc[2][4];
#pragma unroll
    for (int qs = 0; qs < 2; ++qs)
#pragma unroll
      for (int jk = 0; jk < 4; ++jk) sc[qs][jk] = fzero;
    __builtin_amdgcn_s_setprio(1);
#pragma unroll
    for (int ks = 0; ks < 2; ++ks) {
      const int cb = ks * 64 + cbase;
#pragma unroll
      for (int jk = 0; jk < 4; ++jk) {
        const int r = jk * 16 + rl;
        s8v kf = *(const s8v*)(sK[buf] + r * 128 + (cb ^ ((r & 7) << 4)));
        sc[0][jk] = mfma16(kf, qf[0][ks], sc[0][jk]);
        sc[1][jk] = mfma16(kf, qf[1][ks], sc[1][jk]);
      }
    }
    __builtin_amdgcn_s_setprio(0);

    // static-max softmax: P = exp2(sc) (bounded scores; m cancels in O/l)
#pragma unroll
    for (int qs = 0; qs < 2; ++qs) {
      float rs = 0.f;
#pragma unroll
      for (int jk = 0; jk < 4; ++jk)
#pragma unroll
        for (int mm = 0; mm < 4; ++mm) {
          const float p = fexp2(sc[qs][jk][mm]);
          sc[qs][jk][mm] = p;
          rs += p;
        }
      l[qs] += rs;
    }

    // pa fully in-register: fragment jk holds physical keys
    // {32*(jk>>1) + g*8 + 4*(jk&1) + mm}  ->  pa[ks] = sc[2ks] ++ sc[2ks+1].
    s8v pa[2][2];
#pragma unroll
    for (int qs = 0; qs < 2; ++qs) {
#pragma unroll
      for (int ks = 0; ks < 2; ++ks) {
        union { s8v v; unsigned int u[4]; } pk;
        pk.u[0] = cvtpk_bf16(sc[qs][2 * ks][0], sc[qs][2 * ks][1]);
        pk.u[1] = cvtpk_bf16(sc[qs][2 * ks][2], sc[qs][2 * ks][3]);
        pk.u[2] = cvtpk_bf16(sc[qs][2 * ks + 1][0], sc[qs][2 * ks + 1][1]);
        pk.u[3] = cvtpk_bf16(sc[qs][2 * ks + 1][2], sc[qs][2 * ks + 1][3]);
        pa[qs][ks] = pk.v;
      }
    }

    // O += P * V : one vf read feeds both q-subtiles.
    __builtin_amdgcn_s_setprio(1);
#pragma unroll
    for (int ks = 0; ks < 2; ++ks) {
      const int cb = ks * 64 + cbase;
#pragma unroll
      for (int jd = 0; jd < 4; ++jd) {
        const int r = jd * 16 + rl;
        s8v vf = *(const s8v*)(sV[buf] + r * 128 + (cb ^ ((r & 7) << 4)));
        of[0][jd] = mfma16(pa[0][ks], vf, of[0][jd]);
        of[1][jd] = mfma16(pa[1][ks], vf, of[1][jd]);
      }
    }
    __builtin_amdgcn_s_setprio(0);
  }

#pragma unroll
  for (int qs = 0; qs < 2; ++qs) {
    float lt = l[qs];
    lt += __shfl_xor(lt, 16);
    lt += __shfl_xor(lt, 32);
    const float inv = 1.0f / lt;
#pragma unroll
    for (int r = 0; r < 4; ++r) {
      const float ivr = __shfl(inv, g * 20 + r);
      const int qrow = qt * 128 + wave * 32 + qs * 16 + g * 4 + r;
      const size_t obase = ((size_t)b * 2048 + qrow) * 1024 + h * 64;
#pragma unroll
      for (int jd = 0; jd < 4; ++jd) Og[obase + jd * 16 + rl] = f2bf(of[qs][jd][r] * ivr);
    }
  }
}

// ---------------------------------------------------------------------------
extern "C" void kernel_launch(void* const* d_in, const int* in_sizes, int n_in,
                              void* d_out, int out_size, void* d_ws, size_t ws_size,
                              hipStream_t stream) {
  (void)in_sizes; (void)n_in; (void)out_size; (void)ws_size;
  const float* src  = (const float*)d_in[0];
  const float* Wqkv = (const float*)d_in[1];
  const float* Wout = (const float*)d_in[2];
  const float* g1   = (const float*)d_in[3];
  const float* g2   = (const float*)d_in[4];
  const float* W1   = (const float*)d_in[5];
  const float* W2   = (const float*)d_in[6];
  const float* W3   = (const float*)d_in[7];
  float* out = (float*)d_out;

  char* ws = (char*)d_ws;
  size_t off = 0;
  auto take = [&](size_t bytes) -> char* {
    char* p = ws + off;
    off += (bytes + 255) & ~(size_t)255;
    return p;
  };
  unsigned short* wQKV = (unsigned short*)take((size_t)3072 * 1024 * 2);
  unsigned short* wOut = (unsigned short*)take((size_t)1024 * 1024 * 2);
  unsigned short* wI   = (unsigned short*)take((size_t)8192 * 1024 * 2);  // W1/W3 interleaved
  unsigned short* wW2  = (unsigned short*)take((size_t)1024 * 4096 * 2);
  unsigned short* xn   = (unsigned short*)take((size_t)8192 * 1024 * 2);  // xn / attnO / xn2
  unsigned short* q    = (unsigned short*)take((size_t)64 * 2048 * 64 * 2);  // Q heads / xb
  unsigned short* kb   = (unsigned short*)take((size_t)64 * 2048 * 64 * 2);
  unsigned short* vT   = (unsigned short*)take((size_t)64 * 64 * 2048 * 2);
  float* cosT = (float*)take((size_t)2048 * 32 * 4);
  float* sinT = (float*)take((size_t)2048 * 32 * 4);
  unsigned short* h1   = (unsigned short*)take((size_t)8192 * 4096 * 2);  // gelu(h1)*h3

  // merged prep: weight converts + rmsnorm(src,g1) + rope table
  prep_k<<<dim3(24832), dim3(256), 0, stream>>>(Wqkv, Wout, W2, W1, W3,
                                                wQKV, wOut, wW2, wI,
                                                src, g1, xn, cosT, sinT);
  // qkv = xn @ Wqkv^T -> q/k (RoPE fused) + vT (transposed in-epilogue)
  gemm_bt<1><<<dim3(1536), dim3(256), 0, stream>>>(xn, wQKV, 1024, 3072, 24, 8,
                                                   nullptr, nullptr, nullptr, q, kb, vT, cosT, sinT);
  // attnO -> xn  [B,S,1024]  (4 waves, key-permuted K, P in registers)
  attn_k<<<dim3(1024), dim3(256), 0, stream>>>(q, kb, vT, xn);
  // xb = bf16(src + attnO @ Wout^T)   (reuse q buffer)
  gemm_bt<5><<<dim3(512), dim3(256), 0, stream>>>(xn, wOut, 1024, 1024, 8, 4,
                                                  q, nullptr, src, nullptr, nullptr, nullptr,
                                                  nullptr, nullptr);
  // xn2 = rmsnorm(xb, g2)
  rmsnorm_b<<<dim3(8192), dim3(256), 0, stream>>>(q, g2, xn);
  // h1 = gelu(xn2 @ W1^T) * (xn2 @ W3^T)   (fused, interleaved; gw=4: 3MB window)
  gemm_bt<4><<<dim3(4096), dim3(256), 0, stream>>>(xn, wI, 1024, 4096, 64, 4,
                                                   h1, nullptr, nullptr, nullptr, nullptr, nullptr,
                                                   nullptr, nullptr);
  // out = xb + h1 @ W2^T   (f32 final)
  gemm_bt<6><<<dim3(512), dim3(256), 0, stream>>>(h1, wW2, 4096, 1024, 8, 2,
                                                  nullptr, out, nullptr, q, nullptr, nullptr,
                                                  nullptr, nullptr);
}